// Round 1
// baseline (225.626 us; speedup 1.0000x reference)
//
#include <hip/hip_runtime.h>
#include <hip/hip_bf16.h>
#include <math.h>

// IntegralTransform via bf16 MFMA (16x16x32), v2:
//  - pre-pass converts fy (N x 32, f32) -> bf16 in d_ws; main-kernel A-fragments
//    are then single 16B global loads (no bufA staging, half the gather bytes,
//    fy working set 3.2MB fits per-XCD L2).
//  - cross-point software pipeline: next point's nbr / fy-fragments / y[j] /
//    wts[j] are prefetched into registers during the current point's layer-2/3,
//    hiding the gather latency that dominated v1 (all pipes < 60%, occ 37%).
//  - epilogue reads fy16/wts directly (u16 loads + shfl), issued a tile early.
//  - launch_bounds(256,3): kernel is reg-limited to ~3 waves/SIMD anyway
//    (80 regs of weight fragments); give the RA the honest 170-reg budget.

typedef __attribute__((ext_vector_type(8))) short short8;
typedef __attribute__((ext_vector_type(4))) float floatx4;

__device__ __forceinline__ unsigned short bf16rne(float f) {
    unsigned int u = __float_as_uint(f);
    u += 0x7fffu + ((u >> 16) & 1u);
    return (unsigned short)(u >> 16);
}
__device__ __forceinline__ unsigned int pk2(float a, float b) {
    union { __hip_bfloat162 h; unsigned int u; } cv;
    cv.h = __float22bfloat162_rn(make_float2(a, b));
    return cv.u;
}
__device__ __forceinline__ float bf16f(unsigned short u) {
    return __uint_as_float(((unsigned int)u) << 16);
}
// tanh-form gelu, 8 ops: x*(1 - 1/(exp2(c*x*(1+0.044715x^2)) + 1))
__device__ __forceinline__ float gelu_fast(float x) {
    float u = x * fmaf(0.044715f * x, x, 1.0f);
    float e = __expf(1.5957691f * u);   // exp(2z)
    float r = __builtin_amdgcn_rcpf(e + 1.0f);
    return fmaf(-x, r, x);
}

#define MFMA16(a, b, c) __builtin_amdgcn_mfma_f32_16x16x32_bf16(a, b, c, 0, 0, 0)

// ---- pre-pass: f32 -> bf16 (RNE), 8 elems per thread ----
__global__ __launch_bounds__(256) void cvt_bf16(const float* __restrict__ in,
                                                unsigned short* __restrict__ o16,
                                                int n8) {
    int i = blockIdx.x * 256 + threadIdx.x;
    if (i >= n8) return;
    const float4* p = (const float4*)(in + (size_t)i * 8);
    float4 a = p[0], b = p[1];
    *(uint4*)(o16 + (size_t)i * 8) =
        make_uint4(pk2(a.x, a.y), pk2(a.z, a.w), pk2(b.x, b.y), pk2(b.z, b.w));
}

__global__ __launch_bounds__(256, 3) void it_mfma(
    const float* __restrict__ y, const unsigned short* __restrict__ fy16,
    const float* __restrict__ wts,
    const float* __restrict__ W1, const float* __restrict__ b1,
    const float* __restrict__ W2, const float* __restrict__ b2,
    const float* __restrict__ W3, const float* __restrict__ b3,
    const int* __restrict__ nbr,
    float* __restrict__ out, int npts)
{
    __shared__ unsigned short ldsB[4][32][72];   // h1/h2 transpose buffer, 18432 B

    const int lane = threadIdx.x & 63;
    const int wv   = threadIdx.x >> 6;
    const int quad = lane >> 4;
    const int c16  = lane & 15;
    const int wgid   = blockIdx.x * 4 + wv;
    const int nwaves = gridDim.x * 4;
    if (wgid >= npts) return;

    // ---- weight fragments (bf16, B-layout: k = 32*kb + 8*quad + j, n = 16*nb + c16)
    // k-permutation: k'<32 -> W1 row 6+k' (fy block); 32..37 -> rows 0..5; else 0
    short8 w1f[2][4], w2f[2][4], w3f[2][2];
    #pragma unroll
    for (int kb = 0; kb < 2; ++kb)
        #pragma unroll
        for (int nb = 0; nb < 4; ++nb)
            #pragma unroll
            for (int j = 0; j < 8; ++j) {
                int kp = kb * 32 + quad * 8 + j;
                int n  = nb * 16 + c16;
                int r  = (kp < 32) ? (6 + kp) : (kp < 38 ? kp - 32 : -1);
                float v = (r >= 0) ? W1[r * 64 + n] : 0.f;
                w1f[kb][nb][j] = (short)bf16rne(v);
            }
    #pragma unroll
    for (int kb = 0; kb < 2; ++kb)
        #pragma unroll
        for (int nb = 0; nb < 4; ++nb)
            #pragma unroll
            for (int j = 0; j < 8; ++j) {
                int k = kb * 32 + quad * 8 + j;
                w2f[kb][nb][j] = (short)bf16rne(W2[k * 64 + nb * 16 + c16]);
            }
    #pragma unroll
    for (int kb = 0; kb < 2; ++kb)
        #pragma unroll
        for (int nb = 0; nb < 2; ++nb)
            #pragma unroll
            for (int j = 0; j < 8; ++j) {
                int k = kb * 32 + quad * 8 + j;
                w3f[kb][nb][j] = (short)bf16rne(W3[k * 32 + nb * 16 + c16]);
            }
    float b1v[4], b2v[4], b3v[2];
    #pragma unroll
    for (int nb = 0; nb < 4; ++nb) { b1v[nb] = b1[nb * 16 + c16]; b2v[nb] = b2[nb * 16 + c16]; }
    b3v[0] = b3[c16]; b3v[1] = b3[16 + c16];

    unsigned short (*bufB)[72] = ldsB[wv];
    const floatx4 fz = {0.f, 0.f, 0.f, 0.f};

    // ---- prologue: prefetch first point ----
    int p = wgid;
    int   e32 = nbr[p * 32 + (lane & 31)];     // neighbor idx of edge (lane&31)
    float w32 = wts[e32];
    short8 a0c[2];
    float yjc[2][3] = {{0.f,0.f,0.f},{0.f,0.f,0.f}};
    {
        int j0 = __shfl(e32, c16), j1 = __shfl(e32, 16 + c16);
        a0c[0] = *(const short8*)(fy16 + (size_t)j0 * 32 + quad * 8);
        a0c[1] = *(const short8*)(fy16 + (size_t)j1 * 32 + quad * 8);
        if (quad == 0) {
            yjc[0][0] = y[3*j0]; yjc[0][1] = y[3*j0+1]; yjc[0][2] = y[3*j0+2];
            yjc[1][0] = y[3*j1]; yjc[1][1] = y[3*j1+1]; yjc[1][2] = y[3*j1+2];
        }
    }
    float yjn[2][3] = {{0.f,0.f,0.f},{0.f,0.f,0.f}};

    for (;;) {
        const int pu = __builtin_amdgcn_readfirstlane(p);
        const int pn = p + nwaves;
        const bool last = (pn >= npts);
        const int pnc = last ? p : pn;
        int e32n = nbr[pnc * 32 + (lane & 31)];          // issue next-nbr early

        const float yi0 = y[3*pu], yi1 = y[3*pu+1], yi2 = y[3*pu+2];

        // ---- layer 1, both tiles -> bufB rows 0..31 ----
        #pragma unroll
        for (int t = 0; t < 2; ++t) {
            short8 a1 = {0,0,0,0,0,0,0,0};
            if (quad == 0) {
                union { short8 s; unsigned int u[4]; } cv;
                cv.u[0] = pk2(yjc[t][0], yjc[t][1]);
                cv.u[1] = pk2(yjc[t][2], yi0);
                cv.u[2] = pk2(yi1, yi2);
                cv.u[3] = 0u;
                a1 = cv.s;
            }
            floatx4 acc[4];
            #pragma unroll
            for (int nb = 0; nb < 4; ++nb) {
                acc[nb] = MFMA16(a0c[t], w1f[0][nb], fz);
                acc[nb] = MFMA16(a1,     w1f[1][nb], acc[nb]);
            }
            #pragma unroll
            for (int r = 0; r < 4; ++r) {
                float g0 = gelu_fast(acc[0][r] + b1v[0]);
                float g1 = gelu_fast(acc[1][r] + b1v[1]);
                float g2 = gelu_fast(acc[2][r] + b1v[2]);
                float g3 = gelu_fast(acc[3][r] + b1v[3]);
                unsigned int p01 = pk2(g0, g1), p23 = pk2(g2, g3);
                int orow = t * 16 + quad * 4 + r;
                bufB[orow][c16]      = (unsigned short)p01;
                bufB[orow][16 + c16] = (unsigned short)(p01 >> 16);
                bufB[orow][32 + c16] = (unsigned short)p23;
                bufB[orow][48 + c16] = (unsigned short)(p23 >> 16);
            }
        }

        // ---- tile-0 epilogue gathers (issued BEFORE prefetch, so consuming
        //      them doesn't drain the prefetch loads) ----
        unsigned short f0r[2][4], f1r[2][4];
        float wrr[2][4];
        #pragma unroll
        for (int r = 0; r < 4; ++r) {
            int orow = quad * 4 + r;
            int jr = __shfl(e32, orow);
            f0r[0][r] = fy16[(size_t)jr * 32 + c16];
            f1r[0][r] = fy16[(size_t)jr * 32 + 16 + c16];
            wrr[0][r] = __shfl(w32, orow);
        }

        // ---- prefetch next point (hidden under layers 2/3 + epilogue) ----
        short8 a0n[2];
        float w32n;
        {
            int jn0 = __shfl(e32n, c16), jn1 = __shfl(e32n, 16 + c16);
            a0n[0] = *(const short8*)(fy16 + (size_t)jn0 * 32 + quad * 8);
            a0n[1] = *(const short8*)(fy16 + (size_t)jn1 * 32 + quad * 8);
            w32n = wts[e32n];
            if (quad == 0) {
                yjn[0][0] = y[3*jn0]; yjn[0][1] = y[3*jn0+1]; yjn[0][2] = y[3*jn0+2];
                yjn[1][0] = y[3*jn1]; yjn[1][1] = y[3*jn1+1]; yjn[1][2] = y[3*jn1+2];
            }
        }

        // ---- layers 2,3 + epilogue, per tile ----
        float colsum0 = 0.f, colsum1 = 0.f;
        #pragma unroll
        for (int t = 0; t < 2; ++t) {
            if (t == 1) {           // tile-1 epilogue gathers (after prefetch)
                #pragma unroll
                for (int r = 0; r < 4; ++r) {
                    int orow = 16 + quad * 4 + r;
                    int jr = __shfl(e32, orow);
                    f0r[1][r] = fy16[(size_t)jr * 32 + c16];
                    f1r[1][r] = fy16[(size_t)jr * 32 + 16 + c16];
                    wrr[1][r] = __shfl(w32, orow);
                }
            }
            const int arow = t * 16 + c16;
            short8 h0 = *(const short8*)&bufB[arow][quad * 8];
            short8 h1 = *(const short8*)&bufB[arow][32 + quad * 8];
            floatx4 acc[4];
            #pragma unroll
            for (int nb = 0; nb < 4; ++nb) {
                acc[nb] = MFMA16(h0, w2f[0][nb], fz);
                acc[nb] = MFMA16(h1, w2f[1][nb], acc[nb]);
            }
            #pragma unroll
            for (int r = 0; r < 4; ++r) {
                float g0 = gelu_fast(acc[0][r] + b2v[0]);
                float g1 = gelu_fast(acc[1][r] + b2v[1]);
                float g2 = gelu_fast(acc[2][r] + b2v[2]);
                float g3 = gelu_fast(acc[3][r] + b2v[3]);
                unsigned int p01 = pk2(g0, g1), p23 = pk2(g2, g3);
                int orow = t * 16 + quad * 4 + r;
                bufB[orow][c16]      = (unsigned short)p01;
                bufB[orow][16 + c16] = (unsigned short)(p01 >> 16);
                bufB[orow][32 + c16] = (unsigned short)p23;
                bufB[orow][48 + c16] = (unsigned short)(p23 >> 16);
            }
            short8 g0s = *(const short8*)&bufB[arow][quad * 8];
            short8 g1s = *(const short8*)&bufB[arow][32 + quad * 8];
            floatx4 o[2];
            #pragma unroll
            for (int nb = 0; nb < 2; ++nb) {
                o[nb] = MFMA16(g0s, w3f[0][nb], fz);
                o[nb] = MFMA16(g1s, w3f[1][nb], o[nb]);
            }
            #pragma unroll
            for (int r = 0; r < 4; ++r) {
                colsum0 = fmaf((o[0][r] + b3v[0]) * bf16f(f0r[t][r]), wrr[t][r], colsum0);
                colsum1 = fmaf((o[1][r] + b3v[1]) * bf16f(f1r[t][r]), wrr[t][r], colsum1);
            }
        }

        // reduce across quads (rows) and store one point [32 ch]
        colsum0 += __shfl_xor(colsum0, 16, 64);
        colsum0 += __shfl_xor(colsum0, 32, 64);
        colsum1 += __shfl_xor(colsum1, 16, 64);
        colsum1 += __shfl_xor(colsum1, 32, 64);
        if (lane < 32)
            out[pu * 32 + lane] = (lane < 16) ? colsum0 : colsum1;

        if (last) break;
        p = pn;
        e32 = e32n; w32 = w32n;
        a0c[0] = a0n[0]; a0c[1] = a0n[1];
        #pragma unroll
        for (int t = 0; t < 2; ++t)
            #pragma unroll
            for (int k = 0; k < 3; ++k) yjc[t][k] = yjn[t][k];
    }
}

extern "C" void kernel_launch(void* const* d_in, const int* in_sizes, int n_in,
                              void* d_out, int out_size, void* d_ws, size_t ws_size,
                              hipStream_t stream) {
    const float* y  = (const float*)d_in[0];
    const float* fy = (const float*)d_in[1];
    const float* wt = (const float*)d_in[2];
    const float* W1 = (const float*)d_in[3];
    const float* b1 = (const float*)d_in[4];
    const float* W2 = (const float*)d_in[5];
    const float* b2 = (const float*)d_in[6];
    const float* W3 = (const float*)d_in[7];
    const float* b3 = (const float*)d_in[8];
    const int* nbr  = (const int*)d_in[9];
    const int E = in_sizes[9];
    const int npts = E >> 5;              // K = 32 fixed
    float* out = (float*)d_out;

    // fy -> bf16 in workspace (npts*32*2 = 3.2 MB for N=50000)
    unsigned short* fy16 = (unsigned short*)d_ws;
    const int n8 = npts * 4;              // 8 floats per thread
    hipLaunchKernelGGL(cvt_bf16, dim3((n8 + 255) / 256), dim3(256), 0, stream,
                       fy, fy16, n8);

    // persistent: 1024 blocks x 4 waves; reg-limited ~3 waves/SIMD resident
    hipLaunchKernelGGL(it_mfma, dim3(1024), dim3(256), 0, stream,
                       y, fy16, wt, W1, b1, W2, b2, W3, b3, nbr, out, npts);
}

// Round 3
// 199.815 us; speedup vs baseline: 1.1292x; 1.1292x over previous
//
#include <hip/hip_runtime.h>
#include <hip/hip_bf16.h>
#include <math.h>

// IntegralTransform via bf16 MFMA (16x16x32), v3b (v3 + launch-arg fix):
//  - ROOT CAUSE from v1/v2 counters: WRITE_SIZE ~84MB over output = the 80
//    per-lane weight-fragment registers were SPILLED to scratch (80 regs x 4B
//    x 64 lanes x 4096 waves = 84MB of spill writes; fills thrashed L2 ->
//    97MB FETCH and huge exposed latency; residency 3/CU -> straggler tail).
//  - Fix: weights are identical for every wave. Pre-pack B-fragments in MFMA
//    lane order into d_ws (20 frags x 64 lanes x 16B = 20KB), copy once per
//    block into LDS, ds_read_b128 each fragment at its MFMA. woff asm barrier
//    defeats LICM so fragments are never hoisted back into registers.
//  - Register demand ~110 -> launch_bounds(256,4) honest, no spill.
//    LDS 20KB + 18KB bufB = 38.9KB -> 4 blocks/CU; grid = residency x 256 CUs
//    (occupancy API) so there is no tail wave.
//  - keeps v2's wins: fy16 bf16 pre-pass (A-frags = one 16B load), cross-point
//    register prefetch pipeline.

typedef __attribute__((ext_vector_type(8))) short short8;
typedef __attribute__((ext_vector_type(4))) float floatx4;

__device__ __forceinline__ unsigned short bf16rne(float f) {
    unsigned int u = __float_as_uint(f);
    u += 0x7fffu + ((u >> 16) & 1u);
    return (unsigned short)(u >> 16);
}
__device__ __forceinline__ unsigned int pk2(float a, float b) {
    union { __hip_bfloat162 h; unsigned int u; } cv;
    cv.h = __float22bfloat162_rn(make_float2(a, b));
    return cv.u;
}
__device__ __forceinline__ float bf16f(unsigned short u) {
    return __uint_as_float(((unsigned int)u) << 16);
}
// tanh-form gelu: x*(1 - 1/(exp(2*0.7978845608*x*(1+0.044715x^2)) + 1))
__device__ __forceinline__ float gelu_fast(float x) {
    float u = x * fmaf(0.044715f * x, x, 1.0f);
    float e = __expf(1.5957691f * u);
    float r = __builtin_amdgcn_rcpf(e + 1.0f);
    return fmaf(-x, r, x);
}

#define MFMA16(a, b, c) __builtin_amdgcn_mfma_f32_16x16x32_bf16(a, b, c, 0, 0, 0)

// ---- pre-pass 1: fy f32 -> bf16 (RNE), 8 elems per thread ----
__global__ __launch_bounds__(256) void cvt_bf16(const float* __restrict__ in,
                                                unsigned short* __restrict__ o16,
                                                int n8) {
    int i = blockIdx.x * 256 + threadIdx.x;
    if (i >= n8) return;
    const float4* p = (const float4*)(in + (size_t)i * 8);
    float4 a = p[0], b = p[1];
    *(uint4*)(o16 + (size_t)i * 8) =
        make_uint4(pk2(a.x, a.y), pk2(a.z, a.w), pk2(b.x, b.y), pk2(b.z, b.w));
}

// ---- pre-pass 2: pack weight B-fragments in MFMA lane order ----
// frag ids: 0..7 = W1[kb*4+nb], 8..15 = W2[kb*4+nb], 16..19 = W3[kb*2+nb]
// B layout for 16x16x32: k = 32*kb + 8*quad + j, n = 16*nb + c16.
// W1 k-permutation: kp<32 -> row 6+kp (fy block); 32..37 -> rows 0..5; else 0.
__global__ __launch_bounds__(256) void pack_weights(
    const float* __restrict__ W1, const float* __restrict__ W2,
    const float* __restrict__ W3, unsigned short* __restrict__ wpack)
{
    int t = blockIdx.x * 256 + threadIdx.x;
    if (t >= 20 * 64) return;
    int f = t >> 6, lane = t & 63;
    int quad = lane >> 4, c16 = lane & 15;
    unsigned short v8[8];
    if (f < 8) {
        int kb = f >> 2, nb = f & 3;
        #pragma unroll
        for (int j = 0; j < 8; ++j) {
            int kp = kb * 32 + quad * 8 + j;
            int n  = nb * 16 + c16;
            int r  = (kp < 32) ? (6 + kp) : (kp < 38 ? kp - 32 : -1);
            v8[j] = (r >= 0) ? bf16rne(W1[r * 64 + n]) : (unsigned short)0;
        }
    } else if (f < 16) {
        int kb = (f - 8) >> 2, nb = (f - 8) & 3;
        #pragma unroll
        for (int j = 0; j < 8; ++j) {
            int k = kb * 32 + quad * 8 + j;
            v8[j] = bf16rne(W2[k * 64 + nb * 16 + c16]);
        }
    } else {
        int kb = (f - 16) >> 1, nb = (f - 16) & 1;
        #pragma unroll
        for (int j = 0; j < 8; ++j) {
            int k = kb * 32 + quad * 8 + j;
            v8[j] = bf16rne(W3[k * 32 + nb * 16 + c16]);
        }
    }
    uint4 o;
    o.x = (unsigned)v8[0] | ((unsigned)v8[1] << 16);
    o.y = (unsigned)v8[2] | ((unsigned)v8[3] << 16);
    o.z = (unsigned)v8[4] | ((unsigned)v8[5] << 16);
    o.w = (unsigned)v8[6] | ((unsigned)v8[7] << 16);
    *(uint4*)(wpack + (size_t)t * 8) = o;
}

__global__ __launch_bounds__(256, 4) void it_mfma(
    const float* __restrict__ y, const unsigned short* __restrict__ fy16,
    const float* __restrict__ wts,
    const unsigned short* __restrict__ wpack,
    const float* __restrict__ b1, const float* __restrict__ b2,
    const float* __restrict__ b3,
    const int* __restrict__ nbr,
    float* __restrict__ out, int npts)
{
    __shared__ unsigned short wlds[20 * 64 * 8];   // 20480 B, block-shared
    __shared__ unsigned short ldsB[4][32][72];     // 18432 B, per-wave h1/h2

    const int tid  = threadIdx.x;
    const int lane = tid & 63;
    const int wv   = tid >> 6;
    const int quad = lane >> 4;
    const int c16  = lane & 15;
    const int wgid   = blockIdx.x * 4 + wv;
    const int nwaves = gridDim.x * 4;

    // block-cooperative weight load (BEFORE any early exit: barrier safety)
    {
        const uint4* src = (const uint4*)wpack;
        uint4* dst = (uint4*)wlds;
        #pragma unroll
        for (int i = 0; i < 5; ++i)
            dst[tid + i * 256] = src[tid + i * 256];
    }
    __syncthreads();
    if (wgid >= npts) return;

    float b1v[4], b2v[4], b3v[2];
    #pragma unroll
    for (int nb = 0; nb < 4; ++nb) { b1v[nb] = b1[nb * 16 + c16]; b2v[nb] = b2[nb * 16 + c16]; }
    b3v[0] = b3[c16]; b3v[1] = b3[16 + c16];

    unsigned short (*bufB)[72] = ldsB[wv];
    const floatx4 fz = {0.f, 0.f, 0.f, 0.f};

    // ---- prologue: prefetch first point ----
    int p = wgid;
    int   e32 = nbr[p * 32 + (lane & 31)];
    float w32 = wts[e32];
    short8 a0c[2];
    float yjc[2][3] = {{0.f,0.f,0.f},{0.f,0.f,0.f}};
    {
        int j0 = __shfl(e32, c16), j1 = __shfl(e32, 16 + c16);
        a0c[0] = *(const short8*)(fy16 + (size_t)j0 * 32 + quad * 8);
        a0c[1] = *(const short8*)(fy16 + (size_t)j1 * 32 + quad * 8);
        if (quad == 0) {
            yjc[0][0] = y[3*j0]; yjc[0][1] = y[3*j0+1]; yjc[0][2] = y[3*j0+2];
            yjc[1][0] = y[3*j1]; yjc[1][1] = y[3*j1+1]; yjc[1][2] = y[3*j1+2];
        }
    }
    float yjn[2][3] = {{0.f,0.f,0.f},{0.f,0.f,0.f}};

    unsigned woff = 0;   // always 0; asm barrier below makes it loop-variant
                         // so the 20 weight fragments are never LICM-hoisted
                         // back into registers (that's what spilled v1/v2).

    for (;;) {
        asm volatile("" : "+v"(woff));
        const unsigned short* wp = wlds + woff;
        // frag fetch: ds_read_b128, 16B-aligned, offset fits 16-bit imm
        #define WFRAG(fid) (*(const short8*)(wp + (((fid) * 64 + lane) * 8)))

        const int pu = __builtin_amdgcn_readfirstlane(p);
        const int pn = p + nwaves;
        const bool last = (pn >= npts);
        const int pnc = last ? p : pn;
        int e32n = nbr[pnc * 32 + (lane & 31)];          // issue next-nbr early

        const float yi0 = y[3*pu], yi1 = y[3*pu+1], yi2 = y[3*pu+2];

        // ---- layer 1, both tiles -> bufB rows 0..31 ----
        #pragma unroll
        for (int t = 0; t < 2; ++t) {
            short8 a1 = {0,0,0,0,0,0,0,0};
            if (quad == 0) {
                union { short8 s; unsigned int u[4]; } cv;
                cv.u[0] = pk2(yjc[t][0], yjc[t][1]);
                cv.u[1] = pk2(yjc[t][2], yi0);
                cv.u[2] = pk2(yi1, yi2);
                cv.u[3] = 0u;
                a1 = cv.s;
            }
            floatx4 acc[4];
            #pragma unroll
            for (int nb = 0; nb < 4; ++nb) {
                acc[nb] = MFMA16(a0c[t], WFRAG(nb), fz);
                acc[nb] = MFMA16(a1,     WFRAG(4 + nb), acc[nb]);
            }
            #pragma unroll
            for (int r = 0; r < 4; ++r) {
                float g0 = gelu_fast(acc[0][r] + b1v[0]);
                float g1 = gelu_fast(acc[1][r] + b1v[1]);
                float g2 = gelu_fast(acc[2][r] + b1v[2]);
                float g3 = gelu_fast(acc[3][r] + b1v[3]);
                unsigned int p01 = pk2(g0, g1), p23 = pk2(g2, g3);
                int orow = t * 16 + quad * 4 + r;
                bufB[orow][c16]      = (unsigned short)p01;
                bufB[orow][16 + c16] = (unsigned short)(p01 >> 16);
                bufB[orow][32 + c16] = (unsigned short)p23;
                bufB[orow][48 + c16] = (unsigned short)(p23 >> 16);
            }
        }

        // ---- tile-0 epilogue gathers ----
        unsigned short f0r[2][4], f1r[2][4];
        float wrr[2][4];
        #pragma unroll
        for (int r = 0; r < 4; ++r) {
            int orow = quad * 4 + r;
            int jr = __shfl(e32, orow);
            f0r[0][r] = fy16[(size_t)jr * 32 + c16];
            f1r[0][r] = fy16[(size_t)jr * 32 + 16 + c16];
            wrr[0][r] = __shfl(w32, orow);
        }

        // ---- prefetch next point (hidden under layers 2/3 + epilogue) ----
        short8 a0n[2];
        float w32n;
        {
            int jn0 = __shfl(e32n, c16), jn1 = __shfl(e32n, 16 + c16);
            a0n[0] = *(const short8*)(fy16 + (size_t)jn0 * 32 + quad * 8);
            a0n[1] = *(const short8*)(fy16 + (size_t)jn1 * 32 + quad * 8);
            w32n = wts[e32n];
            if (quad == 0) {
                yjn[0][0] = y[3*jn0]; yjn[0][1] = y[3*jn0+1]; yjn[0][2] = y[3*jn0+2];
                yjn[1][0] = y[3*jn1]; yjn[1][1] = y[3*jn1+1]; yjn[1][2] = y[3*jn1+2];
            }
        }

        // ---- layers 2,3 + epilogue, per tile ----
        float colsum0 = 0.f, colsum1 = 0.f;
        #pragma unroll
        for (int t = 0; t < 2; ++t) {
            if (t == 1) {           // tile-1 epilogue gathers
                #pragma unroll
                for (int r = 0; r < 4; ++r) {
                    int orow = 16 + quad * 4 + r;
                    int jr = __shfl(e32, orow);
                    f0r[1][r] = fy16[(size_t)jr * 32 + c16];
                    f1r[1][r] = fy16[(size_t)jr * 32 + 16 + c16];
                    wrr[1][r] = __shfl(w32, orow);
                }
            }
            const int arow = t * 16 + c16;
            short8 h0 = *(const short8*)&bufB[arow][quad * 8];
            short8 h1 = *(const short8*)&bufB[arow][32 + quad * 8];
            floatx4 acc[4];
            #pragma unroll
            for (int nb = 0; nb < 4; ++nb) {
                acc[nb] = MFMA16(h0, WFRAG(8 + nb), fz);
                acc[nb] = MFMA16(h1, WFRAG(12 + nb), acc[nb]);
            }
            #pragma unroll
            for (int r = 0; r < 4; ++r) {
                float g0 = gelu_fast(acc[0][r] + b2v[0]);
                float g1 = gelu_fast(acc[1][r] + b2v[1]);
                float g2 = gelu_fast(acc[2][r] + b2v[2]);
                float g3 = gelu_fast(acc[3][r] + b2v[3]);
                unsigned int p01 = pk2(g0, g1), p23 = pk2(g2, g3);
                int orow = t * 16 + quad * 4 + r;
                bufB[orow][c16]      = (unsigned short)p01;
                bufB[orow][16 + c16] = (unsigned short)(p01 >> 16);
                bufB[orow][32 + c16] = (unsigned short)p23;
                bufB[orow][48 + c16] = (unsigned short)(p23 >> 16);
            }
            short8 g0s = *(const short8*)&bufB[arow][quad * 8];
            short8 g1s = *(const short8*)&bufB[arow][32 + quad * 8];
            floatx4 o[2];
            #pragma unroll
            for (int nb = 0; nb < 2; ++nb) {
                o[nb] = MFMA16(g0s, WFRAG(16 + nb), fz);
                o[nb] = MFMA16(g1s, WFRAG(18 + nb), o[nb]);
            }
            #pragma unroll
            for (int r = 0; r < 4; ++r) {
                colsum0 = fmaf((o[0][r] + b3v[0]) * bf16f(f0r[t][r]), wrr[t][r], colsum0);
                colsum1 = fmaf((o[1][r] + b3v[1]) * bf16f(f1r[t][r]), wrr[t][r], colsum1);
            }
        }
        #undef WFRAG

        // reduce across quads (rows) and store one point [32 ch]
        colsum0 += __shfl_xor(colsum0, 16, 64);
        colsum0 += __shfl_xor(colsum0, 32, 64);
        colsum1 += __shfl_xor(colsum1, 16, 64);
        colsum1 += __shfl_xor(colsum1, 32, 64);
        if (lane < 32)
            out[pu * 32 + lane] = (lane < 16) ? colsum0 : colsum1;

        if (last) break;
        p = pn;
        e32 = e32n; w32 = w32n;
        a0c[0] = a0n[0]; a0c[1] = a0n[1];
        #pragma unroll
        for (int t = 0; t < 2; ++t)
            #pragma unroll
            for (int k = 0; k < 3; ++k) yjc[t][k] = yjn[t][k];
    }
}

extern "C" void kernel_launch(void* const* d_in, const int* in_sizes, int n_in,
                              void* d_out, int out_size, void* d_ws, size_t ws_size,
                              hipStream_t stream) {
    const float* y  = (const float*)d_in[0];
    const float* fy = (const float*)d_in[1];
    const float* wt = (const float*)d_in[2];
    const float* W1 = (const float*)d_in[3];
    const float* b1 = (const float*)d_in[4];
    const float* W2 = (const float*)d_in[5];
    const float* b2 = (const float*)d_in[6];
    const float* W3 = (const float*)d_in[7];
    const float* b3 = (const float*)d_in[8];
    const int* nbr  = (const int*)d_in[9];
    const int E = in_sizes[9];
    const int npts = E >> 5;              // K = 32 fixed
    float* out = (float*)d_out;

    // workspace layout: [0, 20480) packed weight frags; [32768, ...) fy16
    unsigned short* wpack = (unsigned short*)d_ws;
    unsigned short* fy16  = (unsigned short*)((char*)d_ws + 32768);

    hipLaunchKernelGGL(pack_weights, dim3(5), dim3(256), 0, stream,
                       W1, W2, W3, wpack);
    const int n8 = npts * 4;              // 8 floats per thread
    hipLaunchKernelGGL(cvt_bf16, dim3((n8 + 255) / 256), dim3(256), 0, stream,
                       fy, fy16, n8);

    // grid = measured residency x 256 CUs -> persistent, no straggler tail
    static int bpc = 0;
    if (bpc == 0) {
        hipOccupancyMaxActiveBlocksPerMultiprocessor(&bpc, it_mfma, 256, 0);
        if (bpc < 1) bpc = 3;
        if (bpc > 8) bpc = 8;
    }
    int grid = bpc * 256;                 // MI355X: 256 CUs
    hipLaunchKernelGGL(it_mfma, dim3(grid), dim3(256), 0, stream,
                       y, fy16, wt, wpack, b1, b2, b3, nbr, out, npts);
}